// Round 5
// baseline (281.554 us; speedup 1.0000x reference)
//
#include <hip/hip_runtime.h>

// Problem dims (fixed by reference setup_inputs)
constexpr int B = 64, T = 256, I = 2048, H = 4096, O = 1024;

#define DECAY 0.9f
#define THRESH 1.0f

typedef __attribute__((ext_vector_type(8))) __bf16 bf16x8;
typedef __attribute__((ext_vector_type(4))) float f32x4;

// ---------------------------------------------------------------------------
// fp32 -> (hi, lo) bf16 split by truncation. a ~= hi + lo with |err| <~ 2^-16 |a|
// ---------------------------------------------------------------------------
__device__ inline void split_bf16(float a, unsigned short& hi, unsigned short& lo) {
    unsigned int u = __float_as_uint(a);
    hi = (unsigned short)(u >> 16);
    float fhi = __uint_as_float(u & 0xffff0000u);
    lo = (unsigned short)(__float_as_uint(a - fhi) >> 16);
}

// ---------------------------------------------------------------------------
// Kernel 1a: partial batch sums. grid (T*I/4/256, 2): z picks b-range of 32.
// Halves the per-thread dependent stream count vs a single 64-deep loop and
// doubles block count (4 blocks/CU) for latency slack. Pure fp32, no rounding.
// ---------------------------------------------------------------------------
__global__ __launch_bounds__(256) void batch_reduce_part(const float* __restrict__ x,
                                                         float* __restrict__ brp) {
    const int idx = blockIdx.x * 256 + threadIdx.x;   // float4 index in [T*I/4)
    const int zb = blockIdx.y;                        // 0 or 1
    const int plane4 = (T * I) / 4;
    const float4* x4 = (const float4*)x + (size_t)zb * 32 * plane4;
    float4 acc = {0.f, 0.f, 0.f, 0.f};
#pragma unroll 16
    for (int b = 0; b < 32; ++b) {
        float4 v = x4[idx + (size_t)b * plane4];
        acc.x += v.x; acc.y += v.y; acc.z += v.z; acc.w += v.w;
    }
    ((float4*)brp)[(size_t)zb * plane4 + idx] = acc;
}

// ---------------------------------------------------------------------------
// Kernel 1b: combine the two partial planes, scale by 1/B, emit bf16 hi/lo.
// 4 MB read + 2 MB write: ~1 us.
// ---------------------------------------------------------------------------
__global__ __launch_bounds__(256) void batch_combine(const float* __restrict__ brp,
                                                     unsigned short* __restrict__ xh,
                                                     unsigned short* __restrict__ xl) {
    const int idx = blockIdx.x * 256 + threadIdx.x;   // float4 index
    const int plane4 = (T * I) / 4;
    float4 p = ((const float4*)brp)[idx];
    float4 q = ((const float4*)brp)[(size_t)plane4 + idx];
    const float s = 1.0f / (float)B;
    float a[4] = {(p.x + q.x) * s, (p.y + q.y) * s, (p.z + q.z) * s, (p.w + q.w) * s};
    unsigned short hi[4], lo[4];
#pragma unroll
    for (int j = 0; j < 4; ++j) split_bf16(a[j], hi[j], lo[j]);
    uint2 ph, pl;
    ph.x = (unsigned int)hi[0] | ((unsigned int)hi[1] << 16);
    ph.y = (unsigned int)hi[2] | ((unsigned int)hi[3] << 16);
    pl.x = (unsigned int)lo[0] | ((unsigned int)lo[1] << 16);
    pl.y = (unsigned int)lo[2] | ((unsigned int)lo[3] << 16);
    ((uint2*)xh)[idx] = ph;
    ((uint2*)xl)[idx] = pl;
}

// ---------------------------------------------------------------------------
// Kernel 2 (fallback path only): currents[t,h] = b_in[h]
// ---------------------------------------------------------------------------
__global__ __launch_bounds__(256) void cur_init(const float* __restrict__ b_in,
                                                float* __restrict__ cur) {
    const int idx = blockIdx.x * 256 + threadIdx.x;
    const int h4 = idx & (H / 4 - 1);
    ((float4*)cur)[idx] = ((const float4*)b_in)[h4];
}

// ---------------------------------------------------------------------------
// Kernel 3: currents += xbar @ W_in  via bf16 hi/lo 3-pass MFMA (fp32-accurate)
// BM=256(=T: W_in read exactly once), BN=32, BK=32, KSPLIT=4 -> 512 blocks.
// SOFTWARE-PIPELINED: while iter k's 24 MFMAs run, iter k+1's W (4 fp32/thr)
// and A (8 bf16x8/thr) global loads are in flight; W ping-pongs through a
// double LDS buffer, one barrier per K-step. Load latency leaves the
// critical path entirely.
// ---------------------------------------------------------------------------
#define BN 32
#define BK 32
#define KSPLIT 4
#define KCHUNK (I / KSPLIT)     // 512
#define KITERS (KCHUNK / BK)    // 16

__global__ __launch_bounds__(256) void gemm_in(const unsigned short* __restrict__ xh,
                                               const unsigned short* __restrict__ xl,
                                               const float* __restrict__ Wi,   // [I,H]
                                               float* __restrict__ dst,
                                               int useAtomic) {
    __shared__ unsigned short BtH[2][BN][BK + 8];  // [buf][n][k], row stride 40
    __shared__ unsigned short BtL[2][BN][BK + 8];

    const int tid = threadIdx.x;
    const int n0 = blockIdx.x * BN;
    const int split = blockIdx.y;
    const int kBeg = split * KCHUNK;
    const int wave = tid >> 6, lane = tid & 63;
    const int quad = lane >> 4, l16 = lane & 15;
    const int m0 = wave * 64;  // each wave owns a 64-row m-strip (4 m-tiles)

    const int sn = tid & 31;          // staging: n within tile
    const int sk = (tid >> 5) << 2;   // staging: k base (0 or 4) per half-wave... (tid>>5)*4

    // global pointers (advance per K-step)
    const float* wp = Wi + (size_t)(kBeg + sk) * H + n0 + sn;
    const unsigned short* ah[4];
    const unsigned short* al[4];
#pragma unroll
    for (int mi = 0; mi < 4; ++mi) {
        const size_t r = (size_t)(m0 + mi * 16 + l16);
        ah[mi] = xh + r * I + kBeg + quad * 8;
        al[mi] = xl + r * I + kBeg + quad * 8;
    }

    f32x4 acc[4][2];
#pragma unroll
    for (int mi = 0; mi < 4; ++mi)
#pragma unroll
        for (int ni = 0; ni < 2; ++ni) acc[mi][ni] = (f32x4){0.f, 0.f, 0.f, 0.f};

    // ---- prologue: load + stage K-step 0 ----
    float w0 = wp[0], w1 = wp[(size_t)H], w2 = wp[2 * (size_t)H], w3 = wp[3 * (size_t)H];
    bf16x8 cAH[4], cAL[4];
#pragma unroll
    for (int mi = 0; mi < 4; ++mi) { cAH[mi] = *(const bf16x8*)ah[mi]; cAL[mi] = *(const bf16x8*)al[mi]; }
    {
        unsigned short h0, h1, h2, h3, l0, l1, l2, l3;
        split_bf16(w0, h0, l0); split_bf16(w1, h1, l1);
        split_bf16(w2, h2, l2); split_bf16(w3, h3, l3);
        uint2 ph, pl;
        ph.x = (unsigned int)h0 | ((unsigned int)h1 << 16);
        ph.y = (unsigned int)h2 | ((unsigned int)h3 << 16);
        pl.x = (unsigned int)l0 | ((unsigned int)l1 << 16);
        pl.y = (unsigned int)l2 | ((unsigned int)l3 << 16);
        *(uint2*)&BtH[0][sn][sk] = ph;
        *(uint2*)&BtL[0][sn][sk] = pl;
    }
    __syncthreads();

#pragma unroll 2
    for (int it = 0; it < KITERS; ++it) {
        const int buf = it & 1;
        const bool more = (it + 1 < KITERS);

        // ---- issue next K-step's global loads (independent of this step) ----
        float nw0, nw1, nw2, nw3;
        bf16x8 nAH[4], nAL[4];
        if (more) {
            const float* wq = wp + (size_t)(it + 1) * BK * H;
            nw0 = wq[0]; nw1 = wq[(size_t)H]; nw2 = wq[2 * (size_t)H]; nw3 = wq[3 * (size_t)H];
            const int ko = (it + 1) * BK;
#pragma unroll
            for (int mi = 0; mi < 4; ++mi) {
                nAH[mi] = *(const bf16x8*)(ah[mi] + ko);
                nAL[mi] = *(const bf16x8*)(al[mi] + ko);
            }
        }

        // ---- consume current: LDS W-frags + 24 MFMAs ----
        bf16x8 bH[2], bL[2];
#pragma unroll
        for (int ni = 0; ni < 2; ++ni) {
            bH[ni] = *(const bf16x8*)&BtH[buf][ni * 16 + l16][quad * 8];
            bL[ni] = *(const bf16x8*)&BtL[buf][ni * 16 + l16][quad * 8];
        }
#pragma unroll
        for (int mi = 0; mi < 4; ++mi)
#pragma unroll
            for (int ni = 0; ni < 2; ++ni) {
                acc[mi][ni] = __builtin_amdgcn_mfma_f32_16x16x32_bf16(cAL[mi], bH[ni], acc[mi][ni], 0, 0, 0);
                acc[mi][ni] = __builtin_amdgcn_mfma_f32_16x16x32_bf16(cAH[mi], bL[ni], acc[mi][ni], 0, 0, 0);
                acc[mi][ni] = __builtin_amdgcn_mfma_f32_16x16x32_bf16(cAH[mi], bH[ni], acc[mi][ni], 0, 0, 0);
            }

        // ---- stage next W into the other LDS buffer; rotate A regs ----
        if (more) {
            unsigned short h0, h1, h2, h3, l0, l1, l2, l3;
            split_bf16(nw0, h0, l0); split_bf16(nw1, h1, l1);
            split_bf16(nw2, h2, l2); split_bf16(nw3, h3, l3);
            uint2 ph, pl;
            ph.x = (unsigned int)h0 | ((unsigned int)h1 << 16);
            ph.y = (unsigned int)h2 | ((unsigned int)h3 << 16);
            pl.x = (unsigned int)l0 | ((unsigned int)l1 << 16);
            pl.y = (unsigned int)l2 | ((unsigned int)l3 << 16);
            *(uint2*)&BtH[buf ^ 1][sn][sk] = ph;
            *(uint2*)&BtL[buf ^ 1][sn][sk] = pl;
            __syncthreads();
#pragma unroll
            for (int mi = 0; mi < 4; ++mi) { cAH[mi] = nAH[mi]; cAL[mi] = nAL[mi]; }
        }
    }

    // epilogue: C/D layout col=lane&15, row=quad*4+reg (verified m89/m91)
    float* base = useAtomic ? dst : dst + (size_t)split * T * H;
#pragma unroll
    for (int mi = 0; mi < 4; ++mi)
#pragma unroll
        for (int ni = 0; ni < 2; ++ni) {
            const int h = n0 + ni * 16 + l16;
#pragma unroll
            for (int r = 0; r < 4; ++r) {
                const int m = m0 + mi * 16 + quad * 4 + r;
                if (useAtomic) atomicAdd(&base[(size_t)m * H + h], acc[mi][ni][r]);
                else           base[(size_t)m * H + h] = acc[mi][ni][r];
            }
        }
}

// ---------------------------------------------------------------------------
// Kernel 4: fold split-K partials + bias into plane 0 IN-PLACE.
// ---------------------------------------------------------------------------
__global__ __launch_bounds__(256) void reduce_part(float* __restrict__ part,
                                                   const float* __restrict__ b_in,
                                                   int nsplit) {
    const int idx = blockIdx.x * 256 + threadIdx.x;  // float4 idx over T*H/4
    const int h4 = idx & (H / 4 - 1);
    float4 s = ((const float4*)b_in)[h4];
    const int plane4 = T * H / 4;
    for (int sp = 0; sp < nsplit; ++sp) {
        float4 v = ((const float4*)part)[(size_t)sp * plane4 + idx];
        s.x += v.x; s.y += v.y; s.z += v.z; s.w += v.w;
    }
    ((float4*)part)[idx] = s;
}

// ---------------------------------------------------------------------------
// Kernel 5: LIF scan over T. One thread per h (hard parallelism cap H=4096).
// 32-deep load batches double-buffered: batch b+1 in flight during batch b's
// dependent LIF chain. Reads one 4 MB plane (L2/L3-warm from reduce_part).
// ---------------------------------------------------------------------------
__global__ __launch_bounds__(64) void lif_scan(const float* __restrict__ cur, // [T,H]
                                               const float* __restrict__ m0v, // [H]
                                               float* __restrict__ agg) {     // [H]
    const int h = blockIdx.x * 64 + threadIdx.x;
    float m = m0v[h];
    float cnt = 0.f;
    float buf[2][32];
#pragma unroll
    for (int j = 0; j < 32; ++j) buf[0][j] = cur[(size_t)j * H + h];
#pragma unroll
    for (int b = 0; b < 8; ++b) {
        if (b + 1 < 8) {
#pragma unroll
            for (int j = 0; j < 32; ++j)
                buf[(b + 1) & 1][j] = cur[(size_t)((b + 1) * 32 + j) * H + h];
        }
#pragma unroll
        for (int j = 0; j < 32; ++j) {
            m = DECAY * m + buf[b & 1][j];
            if (m > THRESH) { cnt += 1.f; m = 0.f; }
        }
    }
    agg[h] = cnt * (1.0f / (float)T);
}

// ---------------------------------------------------------------------------
// Kernel 6a/6b: out = agg @ W_out + b_out
// ---------------------------------------------------------------------------
__global__ __launch_bounds__(256) void out_init(const float* __restrict__ b_out,
                                                float* __restrict__ out) {
    const int o = blockIdx.x * 256 + threadIdx.x;
    out[o] = b_out[o];
}

__global__ __launch_bounds__(256) void out_gemv(const float* __restrict__ agg,
                                                const float* __restrict__ Wout,  // [H,O]
                                                float* __restrict__ out) {
    const int o = blockIdx.x * 256 + threadIdx.x;
    const int h0 = blockIdx.y * 64;
    float s = 0.f;
#pragma unroll 8
    for (int hh = h0; hh < h0 + 64; ++hh) {
        s += agg[hh] * Wout[(size_t)hh * O + o];
    }
    atomicAdd(&out[o], s);
}

// ---------------------------------------------------------------------------
extern "C" void kernel_launch(void* const* d_in, const int* in_sizes, int n_in,
                              void* d_out, int out_size, void* d_ws, size_t ws_size,
                              hipStream_t stream) {
    const float* x     = (const float*)d_in[0];
    const float* W_in  = (const float*)d_in[1];
    const float* b_in  = (const float*)d_in[2];
    const float* W_out = (const float*)d_in[3];
    const float* b_out = (const float*)d_in[4];
    const float* m0    = (const float*)d_in[5];
    float* out = (float*)d_out;

    // ws: xbar_hi [T*I u16] | xbar_lo [T*I u16] | agg [H f32]
    //     | part [KSPLIT*T*H f32] | brp [2*T*I f32]
    unsigned short* xh = (unsigned short*)d_ws;
    unsigned short* xl = xh + (size_t)T * I;
    float* agg  = (float*)(xl + (size_t)T * I);
    float* part = agg + H;
    float* brp  = part + (size_t)KSPLIT * T * H;

    const size_t need = (size_t)2 * T * I * 2 + (size_t)H * 4
                      + (size_t)KSPLIT * T * H * 4 + (size_t)2 * T * I * 4;
    const int fits = (ws_size >= need) ? 1 : 0;  // ws_size constant -> same path every launch

    if (fits) {
        // 1) batch mean: two b-halves (1024 blocks) then combine to bf16 hi/lo
        dim3 g1((T * I / 4) / 256, 2);
        batch_reduce_part<<<g1, 256, 0, stream>>>(x, brp);
        batch_combine<<<(T * I / 4) / 256, 256, 0, stream>>>(brp, xh, xl);

        // 2) pipelined MFMA GEMM into split-K partial planes
        dim3 g2(H / BN, KSPLIT);
        gemm_in<<<g2, 256, 0, stream>>>(xh, xl, W_in, part, 0);

        // 3) fold partials + bias into plane 0
        reduce_part<<<(T * H / 4) / 256, 256, 0, stream>>>(part, b_in, KSPLIT);
    } else {
        // fallback (small ws): single-plane path with atomic accumulation
        dim3 g1((T * I / 4) / 256, 2);
        batch_reduce_part<<<g1, 256, 0, stream>>>(x, brp);
        batch_combine<<<(T * I / 4) / 256, 256, 0, stream>>>(brp, xh, xl);
        cur_init<<<(T * H / 4) / 256, 256, 0, stream>>>(b_in, part);
        dim3 g2(H / BN, KSPLIT);
        gemm_in<<<g2, 256, 0, stream>>>(xh, xl, W_in, part, 1);
    }

    // 4) LIF scan over T -> agg[h]
    lif_scan<<<H / 64, 64, 0, stream>>>(part, m0, agg);

    // 5) out = agg @ W_out + b_out
    out_init<<<O / 256, 256, 0, stream>>>(b_out, out);
    dim3 g4(O / 256, H / 64);
    out_gemv<<<g4, 256, 0, stream>>>(agg, W_out, out);
}